// Round 11
// baseline (198.867 us; speedup 1.0000x reference)
//
#include <hip/hip_runtime.h>
#include <hip/hip_bf16.h>
#include <math.h>

// fp32 I/O confirmed. index_sample is int32.
// R10 POST-MORTEM: disjoint-partials k_attn fixed the atomic poison (70 -> <44us).
// k_measure now top (44us): ~20us VALU issue (generic __shfl_xor lowers to
// ~3 instrs: xor+lshl+ds_bpermute) + ~20-27us L2 gather floor (671MB @ <=34.5TB/s).
// R11: ds_swizzle single-instr butterflies (0x041F/0x081F/0x101F/0x201F/0x401F);
// k_attn accumulates denominator per-lane across subtiles, ONE final reduce (4x
// fewer shuffles).

#define BB 4
#define LL 2048
#define HH 8
#define DD 64
#define SS 40
#define UU 40
#define CC 64
#define LC (LL/CC)    // 32 (cumsum chunking)

#define KC    64      // staged k-tile rows
#define NCH2  8       // k-chunks (256 rows each)
#define UG    2       // u-groups of 20
#define KSUB  4       // 64-row subtiles per chunk
#define KPAD  68      // K/V LDS row stride (floats)
#define PPAD  68

// single-instruction lane swizzle (BitMode: offset = xor_mask<<10 | 0x1F)
#define SWZ(x, pat) __int_as_float(__builtin_amdgcn_ds_swizzle(__float_as_int(x), (pat)))

// ---------------------------------------------------------------------------
// K1: sparsity measure M[bh*L + i] = max_s(Q_i . K_idx[i,s]) - sum_s(...)/L
// one wave per query. lane = (sg = lane>>4, d4 = lane&15); 4 samples/iter.
// Reduce over 16 d4-lanes via ds_swizzle (1 instr/level, no addr VALU ops).
// ---------------------------------------------------------------------------
__global__ void k_measure(const float* __restrict__ Q, const float* __restrict__ K,
                          const int* __restrict__ idx, float* __restrict__ M)
{
    int tid  = threadIdx.x;
    int lane = tid & 63;
    int wave = tid >> 6;
    int qid  = blockIdx.x * 4 + wave;          // qid = bh*L + i
    int bh = qid / LL;  int i = qid - bh * LL;
    int b  = bh / HH;   int h = bh - b * HH;

    int sg = lane >> 4;                        // sample group 0..3
    int d4 = lane & 15;                        // float4 slice of d

    const float* qrow = Q + (((size_t)b * LL + i) * HH + h) * DD;
    float4 qv = *(const float4*)(qrow + d4 * 4);

    const float* Kh = K + ((size_t)b * LL * HH + h) * DD;   // + kk*HH*DD
    const int* ip = idx + (size_t)i * SS;

    float maxv = -INFINITY, sumv = 0.f;
    #pragma unroll
    for (int s0 = 0; s0 < SS; s0 += 4) {
        int kk = ip[s0 + sg];                  // 4 distinct addrs, 16-lane broadcast
        const float* krow = Kh + (size_t)kk * (HH * DD);
        float4 kv = *(const float4*)(krow + d4 * 4);
        float p = qv.x * kv.x;
        p = fmaf(qv.y, kv.y, p);
        p = fmaf(qv.z, kv.z, p);
        p = fmaf(qv.w, kv.w, p);
        // reduce over the 16 d4-lanes (xor 1,2,4,8 stays within sample group)
        p += SWZ(p, 0x041F);
        p += SWZ(p, 0x081F);
        p += SWZ(p, 0x101F);
        p += SWZ(p, 0x201F);
        maxv = fmaxf(maxv, p);
        sumv += p;
    }
    // combine the 4 sample groups (xor16 within 32-half, then cross-half)
    maxv = fmaxf(maxv, SWZ(maxv, 0x401F));
    sumv += SWZ(sumv, 0x401F);
    maxv = fmaxf(maxv, __shfl_xor(maxv, 32));
    sumv += __shfl_xor(sumv, 32);

    if (lane == 0) M[qid] = maxv - sumv * (1.0f / (float)LL);
}

// ---------------------------------------------------------------------------
// K2: top-40 per (b,h). One WAVE per bh, 2048 orderable keys in registers.
// Binary search for rank-40 threshold + idx tiebreak; zero LDS/barriers.
// ---------------------------------------------------------------------------
__global__ void k_topk(const float* __restrict__ M, int* __restrict__ topIdx)
{
    int lane = threadIdx.x;      // 64
    int bh   = blockIdx.x;
    const float* Mp = M + (size_t)bh * LL;

    unsigned k[32];
    #pragma unroll
    for (int r = 0; r < 32; ++r) {
        unsigned u = __float_as_uint(Mp[r * 64 + lane]);
        k[r] = (u & 0x80000000u) ? ~u : (u | 0x80000000u);  // order-preserving
    }

    unsigned T = 0u;
    for (int bit = 31; bit >= 0; --bit) {
        unsigned cand = T | (1u << bit);
        int c = 0;
        #pragma unroll
        for (int r = 0; r < 32; ++r) c += (k[r] >= cand) ? 1 : 0;
        #pragma unroll
        for (int off = 1; off < 64; off <<= 1) c += __shfl_xor(c, off);
        if (c >= UU) T = cand;
    }

    int cGT = 0, cGE = 0;
    #pragma unroll
    for (int r = 0; r < 32; ++r) {
        cGT += (k[r] > T) ? 1 : 0;
        cGE += (k[r] >= T) ? 1 : 0;
    }
    #pragma unroll
    for (int off = 1; off < 64; off <<= 1) {
        cGT += __shfl_xor(cGT, off);
        cGE += __shfl_xor(cGE, off);
    }

    int need = UU - cGT;
    int X = LL;
    if (cGE - cGT != need) {
        int lo2 = 0;
        for (int bit = 10; bit >= 0; --bit) {
            int cand = lo2 | (1 << bit);
            int c = 0;
            #pragma unroll
            for (int r = 0; r < 32; ++r)
                c += (k[r] == T && (r * 64 + lane) < cand) ? 1 : 0;
            #pragma unroll
            for (int off = 1; off < 64; off <<= 1) c += __shfl_xor(c, off);
            if (c < need) lo2 = cand;
        }
        X = lo2 + 1;
    }

    unsigned inMask = 0u;
    int cnt = 0;
    #pragma unroll
    for (int r = 0; r < 32; ++r) {
        bool in = (k[r] > T) || (k[r] == T && (r * 64 + lane) < X);
        if (in) { inMask |= 1u << r; ++cnt; }
    }
    int pre = cnt;
    #pragma unroll
    for (int off = 1; off < 64; off <<= 1) {
        int v = __shfl_up(pre, off);
        if (lane >= off) pre += v;
    }
    int slot = pre - cnt;
    #pragma unroll
    for (int r = 0; r < 32; ++r) {
        if ((inMask >> r) & 1u) {
            topIdx[bh * UU + slot] = r * 64 + lane;
            ++slot;
        }
    }
}

// ---------------------------------------------------------------------------
// K3: attention partials, shift-free softmax, NON-ATOMIC disjoint writes.
// Grid = bh(32) x ch(8) x ug(2) = 512 blocks, 256 threads.
// Denominator: per-lane accumulation across subtiles, ONE final reduce.
// ---------------------------------------------------------------------------
__launch_bounds__(256, 3)
__global__ void k_attn(const float* __restrict__ Q, const float* __restrict__ K,
                       const float* __restrict__ V, const int* __restrict__ topIdx,
                       float* __restrict__ Oc, float* __restrict__ Lc)
{
    __shared__ float sK[KC][KPAD];
    __shared__ float sV[KC][KPAD];
    __shared__ float sP[20][PPAD];
    __shared__ int   sPos[UU];

    int t   = threadIdx.x;
    int bid = blockIdx.x;
    int bh  = bid / (NCH2 * UG);
    int rem = bid % (NCH2 * UG);
    int ch  = rem / UG, ug = rem % UG;
    int b   = bh / HH, h = bh % HH;

    if (t < UU) sPos[t] = topIdx[bh * UU + t];

    int j  = t & 63;                 // QK lane -> k-row within subtile
    int w  = t >> 6, lane = t & 63;  // wave mapping
    int ub = __builtin_amdgcn_readfirstlane(w) * 5;   // local u base (0,5,10,15)

    // PV accumulators: thread = (d4p = t&15, tg = t>>4); local u = tg, 16+tg
    int d4p = t & 15, tg = t >> 4;
    float4 a0 = {0,0,0,0}, a1 = {0,0,0,0};
    float den[5] = {0.f, 0.f, 0.f, 0.f, 0.f};   // per-LANE partials

    for (int sub = 0; sub < KSUB; ++sub) {
        int k0 = (ch * KSUB + sub) * KC;
        __syncthreads();   // previous PV done reading sP/sV (and sPos ready)

        // ---- stage K/V subtile (64 rows x 64 floats), coalesced float4 ----
        const float* Kbase = K + (((size_t)b * LL + k0) * HH + h) * DD;
        const float* Vbase = V + (((size_t)b * LL + k0) * HH + h) * DD;
        #pragma unroll
        for (int it = 0; it < 4; ++it) {
            int flat = it * 256 + t;            // 0..1023
            int r = flat >> 4, d4 = flat & 15;
            float4 kk = *(const float4*)(Kbase + (size_t)r * (HH * DD) + d4 * 4);
            float4 vv = *(const float4*)(Vbase + (size_t)r * (HH * DD) + d4 * 4);
            *(float4*)&sK[r][d4 * 4] = kk;
            *(float4*)&sV[r][d4 * 4] = vv;
        }
        __syncthreads();

        // ---- QK: lane owns k-row j; Q rows via scalar (wave-uniform) loads ----
        int jg = k0 + j;
        float kreg[DD];
        #pragma unroll
        for (int d4 = 0; d4 < 16; ++d4) {
            float4 kk = *(const float4*)&sK[j][d4 * 4];
            kreg[d4 * 4 + 0] = kk.x; kreg[d4 * 4 + 1] = kk.y;
            kreg[d4 * 4 + 2] = kk.z; kreg[d4 * 4 + 3] = kk.w;
        }
        {
            int p0 = __builtin_amdgcn_readfirstlane(sPos[ug * 20 + ub + 0]);
            int p1 = __builtin_amdgcn_readfirstlane(sPos[ug * 20 + ub + 1]);
            int p2 = __builtin_amdgcn_readfirstlane(sPos[ug * 20 + ub + 2]);
            int p3 = __builtin_amdgcn_readfirstlane(sPos[ug * 20 + ub + 3]);
            int p4 = __builtin_amdgcn_readfirstlane(sPos[ug * 20 + ub + 4]);
            const float* q0 = Q + (((size_t)b * LL + p0) * HH + h) * DD;
            const float* q1 = Q + (((size_t)b * LL + p1) * HH + h) * DD;
            const float* q2 = Q + (((size_t)b * LL + p2) * HH + h) * DD;
            const float* q3 = Q + (((size_t)b * LL + p3) * HH + h) * DD;
            const float* q4 = Q + (((size_t)b * LL + p4) * HH + h) * DD;
            float c0 = 0.f, c1 = 0.f, c2 = 0.f, c3 = 0.f, c4 = 0.f;
            #pragma unroll
            for (int d = 0; d < DD; ++d) {
                float kd = kreg[d];
                c0 = fmaf(q0[d], kd, c0);
                c1 = fmaf(q1[d], kd, c1);
                c2 = fmaf(q2[d], kd, c2);
                c3 = fmaf(q3[d], kd, c3);
                c4 = fmaf(q4[d], kd, c4);
            }
            float e0 = (jg > p0) ? 0.f : __expf(c0 * 0.125f);
            float e1 = (jg > p1) ? 0.f : __expf(c1 * 0.125f);
            float e2 = (jg > p2) ? 0.f : __expf(c2 * 0.125f);
            float e3 = (jg > p3) ? 0.f : __expf(c3 * 0.125f);
            float e4 = (jg > p4) ? 0.f : __expf(c4 * 0.125f);
            sP[ub + 0][j] = e0;
            sP[ub + 1][j] = e1;
            sP[ub + 2][j] = e2;
            sP[ub + 3][j] = e3;
            sP[ub + 4][j] = e4;
            den[0] += e0; den[1] += e1; den[2] += e2; den[3] += e3; den[4] += e4;
        }
        __syncthreads();

        // ---- PV accumulate (reads sP/sV only) ----
        #pragma unroll 4
        for (int j4 = 0; j4 < KC / 4; ++j4) {
            float4 pj0 = *(const float4*)&sP[tg][j4 * 4];
            float4 pj1 = (tg < 4) ? *(const float4*)&sP[16 + tg][j4 * 4]
                                  : (float4){0,0,0,0};
            float4 va = *(const float4*)&sV[j4 * 4 + 0][d4p * 4];
            float4 vb = *(const float4*)&sV[j4 * 4 + 1][d4p * 4];
            float4 vc = *(const float4*)&sV[j4 * 4 + 2][d4p * 4];
            float4 vd = *(const float4*)&sV[j4 * 4 + 3][d4p * 4];
            a0.x = fmaf(pj0.x, va.x, fmaf(pj0.y, vb.x, fmaf(pj0.z, vc.x, fmaf(pj0.w, vd.x, a0.x))));
            a0.y = fmaf(pj0.x, va.y, fmaf(pj0.y, vb.y, fmaf(pj0.z, vc.y, fmaf(pj0.w, vd.y, a0.y))));
            a0.z = fmaf(pj0.x, va.z, fmaf(pj0.y, vb.z, fmaf(pj0.z, vc.z, fmaf(pj0.w, vd.z, a0.z))));
            a0.w = fmaf(pj0.x, va.w, fmaf(pj0.y, vb.w, fmaf(pj0.z, vc.w, fmaf(pj0.w, vd.w, a0.w))));
            a1.x = fmaf(pj1.x, va.x, fmaf(pj1.y, vb.x, fmaf(pj1.z, vc.x, fmaf(pj1.w, vd.x, a1.x))));
            a1.y = fmaf(pj1.x, va.y, fmaf(pj1.y, vb.y, fmaf(pj1.z, vc.y, fmaf(pj1.w, vd.y, a1.y))));
            a1.z = fmaf(pj1.x, va.z, fmaf(pj1.y, vb.z, fmaf(pj1.z, vc.z, fmaf(pj1.w, vd.z, a1.z))));
            a1.w = fmaf(pj1.x, va.w, fmaf(pj1.y, vb.w, fmaf(pj1.z, vc.w, fmaf(pj1.w, vd.w, a1.w))));
        }
    }

    // ---- single final denominator reduce (ds_swizzle butterflies) ----
    #pragma unroll
    for (int i = 0; i < 5; ++i) {
        float d = den[i];
        d += SWZ(d, 0x041F);
        d += SWZ(d, 0x081F);
        d += SWZ(d, 0x101F);
        d += SWZ(d, 0x201F);
        d += SWZ(d, 0x401F);
        d += __shfl_xor(d, 32);
        den[i] = d;
    }
    if (lane == 0) {
        int base = (bh * NCH2 + ch) * UU + ug * 20 + ub;
        Lc[base + 0] = den[0]; Lc[base + 1] = den[1]; Lc[base + 2] = den[2];
        Lc[base + 3] = den[3]; Lc[base + 4] = den[4];
    }

    // ---- disjoint final writes ----
    {
        int u0g = ug * 20 + tg;
        size_t o0 = ((size_t)(bh * NCH2 + ch) * UU + u0g) * DD + d4p * 4;
        *(float4*)(Oc + o0) = a0;
        if (tg < 4) {
            int u1g = ug * 20 + 16 + tg;
            size_t o1 = ((size_t)(bh * NCH2 + ch) * UU + u1g) * DD + d4p * 4;
            *(float4*)(Oc + o1) = a1;
        }
    }
}

// ---------------------------------------------------------------------------
// K4a: per-chunk sums of V along L (for cumsum), float4 lanes.
// ---------------------------------------------------------------------------
__global__ void k_chunksum(const float* __restrict__ V, float* __restrict__ chunkSum)
{
    int t  = threadIdx.x;
    int c  = blockIdx.x % CC;
    int bh = blockIdx.x / CC;
    int b  = bh / HH; int h = bh - b * HH;
    int d4 = t & 15, rs = t >> 4;

    float4 acc = {0,0,0,0};
    int l0 = c * LC;
    for (int l = l0 + rs; l < l0 + LC; l += 4) {
        float4 v = *(const float4*)(V + (((size_t)b * LL + l) * HH + h) * DD + d4 * 4);
        acc.x += v.x; acc.y += v.y; acc.z += v.z; acc.w += v.w;
    }
    acc.x += __shfl_xor(acc.x, 16); acc.y += __shfl_xor(acc.y, 16);
    acc.z += __shfl_xor(acc.z, 16); acc.w += __shfl_xor(acc.w, 16);
    acc.x += __shfl_xor(acc.x, 32); acc.y += __shfl_xor(acc.y, 32);
    acc.z += __shfl_xor(acc.z, 32); acc.w += __shfl_xor(acc.w, 32);
    if (t < 16)
        *(float4*)(chunkSum + ((size_t)bh * CC + c) * DD + d4 * 4) = acc;
}

// ---------------------------------------------------------------------------
// K4b: cumsum with chunk-offset, float4 lanes, fp32 output (B,L,H,D).
// ---------------------------------------------------------------------------
__global__ void k_cumsum(const float* __restrict__ V, const float* __restrict__ chunkSum,
                         float* __restrict__ out)
{
    int t  = threadIdx.x;
    int bh = blockIdx.x / (CC / 4);
    int cg = blockIdx.x % (CC / 4);
    int b  = bh / HH; int h = bh - b * HH;
    int d4 = t & 15;
    int c  = cg * 4 + (t >> 4);

    const float4* CS4 = (const float4*)chunkSum;
    float4 acc = {0,0,0,0};
    for (int c2 = 0; c2 < c; ++c2) {
        float4 s = CS4[((size_t)bh * CC + c2) * 16 + d4];
        acc.x += s.x; acc.y += s.y; acc.z += s.z; acc.w += s.w;
    }

    int l0 = c * LC;
    for (int l = l0; l < l0 + LC; ++l) {
        size_t p = (((size_t)b * LL + l) * HH + h) * DD + d4 * 4;
        float4 v = *(const float4*)(V + p);
        acc.x += v.x; acc.y += v.y; acc.z += v.z; acc.w += v.w;
        *(float4*)(out + p) = acc;
    }
}

// ---------------------------------------------------------------------------
// K5: finalize — out[pos] = (sum_ch Oc) / (sum_ch Lc). After k_cumsum.
// ---------------------------------------------------------------------------
__global__ void k_finalize(const float* __restrict__ Oc, const float* __restrict__ Lc,
                           const int* __restrict__ topIdx, float* __restrict__ out)
{
    int bh = blockIdx.x;
    int b  = bh / HH, h = bh % HH;
    int t  = threadIdx.x;
    int d  = t & 63, w = t >> 6;
    for (int i = 0; i < 10; ++i) {
        int u = w * 10 + i;
        int pos = topIdx[bh * UU + u];
        float num = 0.f, den = 0.f;
        #pragma unroll
        for (int c = 0; c < NCH2; ++c) {
            num += Oc[((size_t)(bh * NCH2 + c) * UU + u) * DD + d];
            den += Lc[(bh * NCH2 + c) * UU + u];
        }
        out[(((size_t)b * LL + pos) * HH + h) * DD + d] = num / den;
    }
}

// ---------------------------------------------------------------------------
extern "C" void kernel_launch(void* const* d_in, const int* in_sizes, int n_in,
                              void* d_out, int out_size, void* d_ws, size_t ws_size,
                              hipStream_t stream)
{
    const float* Q   = (const float*)d_in[0];
    const float* K   = (const float*)d_in[1];
    const float* V   = (const float*)d_in[2];
    const int*   idx = (const int*)d_in[3];
    float* out = (float*)d_out;

    // ws layout (floats) — total ~864K floats ≈ 3.45 MB
    float* M        = (float*)d_ws;                               // 65536
    int*   topIdx   = (int*)(M + (size_t)BB * HH * LL);           // 1280
    float* Oc       = (float*)(topIdx + BB * HH * UU);            // 655360
    float* Lc       = Oc + (size_t)BB * HH * NCH2 * UU * DD;      // 10240
    float* chunkSum = Lc + BB * HH * NCH2 * UU;                   // 131072

    k_measure <<<BB * HH * LL / 4,     256, 0, stream>>>(Q, K, idx, M);
    k_topk    <<<BB * HH,               64, 0, stream>>>(M, topIdx);
    k_attn    <<<BB * HH * NCH2 * UG, 256, 0, stream>>>(Q, K, V, topIdx, Oc, Lc);
    k_chunksum<<<BB * HH * CC,          64, 0, stream>>>(V, chunkSum);
    k_cumsum  <<<BB * HH * (CC/4),      64, 0, stream>>>(V, chunkSum, out);
    k_finalize<<<BB * HH,              256, 0, stream>>>(Oc, Lc, topIdx, out);
}